// Round 1
// baseline (248.563 us; speedup 1.0000x reference)
//
#include <hip/hip_runtime.h>

// Chamfer distance, B=8, N=M=8192, D=3, fp32.
// out = mean_b[ mean_n min_m ||p-g||^2 + mean_m min_n ||p-g||^2 ]
//     = (sum(minP) + sum(minG)) / (B*N)

constexpr int B   = 8;
constexpr int N   = 8192;   // points per cloud (pred and gt both 8192)
constexpr int TPB = 256;    // threads per block
constexpr int QPT = 4;      // query points per thread
constexpr int QPB = TPB * QPT;  // 1024 query points per block
constexpr int RCH = 2048;   // reference points staged in LDS per block

__global__ __launch_bounds__(TPB) void init_min_kernel(unsigned int* mins, int n) {
    int i = blockIdx.x * blockDim.x + threadIdx.x;
    if (i < n) mins[i] = 0x7f800000u;  // +inf
}

__global__ __launch_bounds__(TPB) void chamfer_min_kernel(
    const float* __restrict__ pred, const float* __restrict__ gt,
    unsigned int* __restrict__ minP, unsigned int* __restrict__ minG) {
    // grid: 2 dirs x B x (N/QPB) x (N/RCH)
    constexpr int NQ = N / QPB;  // 8
    constexpr int NR = N / RCH;  // 4

    int bid = blockIdx.x;
    int dir = bid / (B * NQ * NR);
    int rem = bid % (B * NQ * NR);
    int b   = rem / (NQ * NR);
    rem     = rem % (NQ * NR);
    int qc  = rem / NR;          // query chunk
    int rc  = rem % NR;          // reference chunk

    const float* Q = (dir == 0) ? pred : gt;
    const float* R = (dir == 0) ? gt : pred;
    unsigned int* outMin = (dir == 0) ? minP : minG;

    __shared__ float4 lds[RCH];  // 32 KB

    // Stage reference chunk (x,y,z,pad) into LDS.
    const float* rbase = R + ((size_t)b * N + (size_t)rc * RCH) * 3;
    for (int e = threadIdx.x; e < RCH; e += TPB) {
        float x = rbase[e * 3 + 0];
        float y = rbase[e * 3 + 1];
        float z = rbase[e * 3 + 2];
        lds[e] = make_float4(x, y, z, 0.0f);
    }
    __syncthreads();

    // Load query points into registers.
    float qx[QPT], qy[QPT], qz[QPT], mn[QPT];
    const float* qbase = Q + ((size_t)b * N + (size_t)qc * QPB) * 3;
    #pragma unroll
    for (int q = 0; q < QPT; ++q) {
        int n = q * TPB + threadIdx.x;
        qx[q] = qbase[n * 3 + 0];
        qy[q] = qbase[n * 3 + 1];
        qz[q] = qbase[n * 3 + 2];
        mn[q] = __builtin_inff();
    }

    // Main loop: broadcast-read each staged reference point, update 4 mins.
    #pragma unroll 2
    for (int j = 0; j < RCH; ++j) {
        float4 g = lds[j];
        #pragma unroll
        for (int q = 0; q < QPT; ++q) {
            float dx = qx[q] - g.x;
            float dy = qy[q] - g.y;
            float dz = qz[q] - g.z;
            float d  = dx * dx;
            d = fmaf(dy, dy, d);
            d = fmaf(dz, dz, d);
            mn[q] = fminf(mn[q], d);
        }
    }

    // Merge partial mins (dists >= 0, so uint order == float order).
    #pragma unroll
    for (int q = 0; q < QPT; ++q) {
        int n = qc * QPB + q * TPB + threadIdx.x;
        atomicMin(&outMin[b * N + n], __float_as_uint(mn[q]));
    }
}

__global__ __launch_bounds__(1024) void chamfer_reduce_kernel(
    const unsigned int* __restrict__ mins, float* __restrict__ out, int total) {
    float s = 0.0f;
    for (int i = threadIdx.x; i < total; i += 1024)
        s += __uint_as_float(mins[i]);
    #pragma unroll
    for (int off = 32; off > 0; off >>= 1)
        s += __shfl_down(s, off, 64);
    __shared__ float wsum[16];
    int lane = threadIdx.x & 63;
    int wv   = threadIdx.x >> 6;
    if (lane == 0) wsum[wv] = s;
    __syncthreads();
    if (threadIdx.x == 0) {
        float t = 0.0f;
        #pragma unroll
        for (int w = 0; w < 16; ++w) t += wsum[w];
        out[0] = t / (float)(B * N);
    }
}

extern "C" void kernel_launch(void* const* d_in, const int* in_sizes, int n_in,
                              void* d_out, int out_size, void* d_ws, size_t ws_size,
                              hipStream_t stream) {
    const float* pred = (const float*)d_in[0];
    const float* gt   = (const float*)d_in[1];
    unsigned int* minP = (unsigned int*)d_ws;
    unsigned int* minG = minP + (size_t)B * N;
    float* out = (float*)d_out;

    int total = 2 * B * N;  // 131072
    init_min_kernel<<<(total + TPB - 1) / TPB, TPB, 0, stream>>>(minP, total);

    int blocks = 2 * B * (N / QPB) * (N / RCH);  // 512
    chamfer_min_kernel<<<blocks, TPB, 0, stream>>>(pred, gt, minP, minG);

    chamfer_reduce_kernel<<<1, 1024, 0, stream>>>(minP, out, total);
}

// Round 3
// 145.233 us; speedup vs baseline: 1.7115x; 1.7115x over previous
//
#include <hip/hip_runtime.h>

// Chamfer distance, B=8, N=M=8192, D=3, fp32.
// dist(p,g) = p^2 + g^2 - 2 p.g  (same expansion as the JAX reference)
// Per query p: min_g dist = p^2 + min_g (g^2 - 2 p.g)   -> 3 FMA + min per pair.

constexpr int B   = 8;
constexpr int N   = 8192;
constexpr int TPB = 256;
constexpr int QPT = 8;            // query points per thread
constexpr int QPB = TPB * QPT;    // 2048 queries per block
constexpr int RCH = 512;          // reference points staged in LDS per block
constexpr int NQ  = N / QPB;      // 4
constexpr int NR  = N / RCH;      // 16

// Order-preserving float->uint encoding (works for negatives too).
__device__ __forceinline__ unsigned int f2u_ord(float f) {
    unsigned int u = __float_as_uint(f);
    return (u & 0x80000000u) ? ~u : (u | 0x80000000u);
}
__device__ __forceinline__ float u2f_ord(unsigned int k) {
    unsigned int u = (k & 0x80000000u) ? (k & 0x7FFFFFFFu) : ~k;
    return __uint_as_float(u);
}

__global__ __launch_bounds__(TPB) void init_kernel(unsigned int* mins, int n, float* out) {
    int i = blockIdx.x * blockDim.x + threadIdx.x;
    if (i < n) mins[i] = 0xFF800000u;  // f2u_ord(+inf)
    if (i == 0) out[0] = 0.0f;
}

__global__ __launch_bounds__(TPB) void chamfer_min_kernel(
    const float* __restrict__ pred, const float* __restrict__ gt,
    unsigned int* __restrict__ minP, unsigned int* __restrict__ minG) {
    // grid: 2 dirs x B x NQ x NR = 1024 blocks
    int bid = blockIdx.x;
    int dir = bid / (B * NQ * NR);
    int rem = bid % (B * NQ * NR);
    int b   = rem / (NQ * NR);
    rem     = rem % (NQ * NR);
    int qc  = rem / NR;
    int rc  = rem % NR;

    const float* Q = (dir == 0) ? pred : gt;
    const float* R = (dir == 0) ? gt : pred;
    unsigned int* outMin = (dir == 0) ? minP : minG;

    __shared__ float4 lds[RCH];  // 8 KB: (gx, gy, gz, g^2)

    const float* rbase = R + ((size_t)b * N + (size_t)rc * RCH) * 3;
    for (int e = threadIdx.x; e < RCH; e += TPB) {
        float x = rbase[e * 3 + 0];
        float y = rbase[e * 3 + 1];
        float z = rbase[e * 3 + 2];
        float g2 = x * x + y * y + z * z;
        lds[e] = make_float4(x, y, z, g2);
    }
    __syncthreads();

    // Query registers: -2*q and |q|^2
    float m2x[QPT], m2y[QPT], m2z[QPT], q2[QPT], mn[QPT];
    const float* qbase = Q + ((size_t)b * N + (size_t)qc * QPB) * 3;
    #pragma unroll
    for (int q = 0; q < QPT; ++q) {
        int n = q * TPB + threadIdx.x;
        float x = qbase[n * 3 + 0];
        float y = qbase[n * 3 + 1];
        float z = qbase[n * 3 + 2];
        m2x[q] = -2.0f * x;
        m2y[q] = -2.0f * y;
        m2z[q] = -2.0f * z;
        q2[q]  = x * x + y * y + z * z;
        mn[q]  = __builtin_inff();
    }

    // Main loop: 2 reference points per iteration, min3 merge.
    #pragma unroll 2
    for (int j = 0; j < RCH; j += 2) {
        float4 g0 = lds[j];
        float4 g1 = lds[j + 1];
        #pragma unroll
        for (int q = 0; q < QPT; ++q) {
            float t0 = fmaf(m2x[q], g0.x, g0.w);
            t0 = fmaf(m2y[q], g0.y, t0);
            t0 = fmaf(m2z[q], g0.z, t0);
            float t1 = fmaf(m2x[q], g1.x, g1.w);
            t1 = fmaf(m2y[q], g1.y, t1);
            t1 = fmaf(m2z[q], g1.z, t1);
            mn[q] = fminf(mn[q], fminf(t0, t1));  // -> v_min3_f32
        }
    }

    #pragma unroll
    for (int q = 0; q < QPT; ++q) {
        int n = qc * QPB + q * TPB + threadIdx.x;
        atomicMin(&outMin[b * N + n], f2u_ord(q2[q] + mn[q]));
    }
}

__global__ __launch_bounds__(TPB) void chamfer_reduce_kernel(
    const unsigned int* __restrict__ mins, float* __restrict__ out, int total) {
    // grid: 128 blocks x 256 threads, 4 elements/thread
    int i0 = blockIdx.x * blockDim.x + threadIdx.x;
    int stride = gridDim.x * blockDim.x;
    float s = 0.0f;
    for (int i = i0; i < total; i += stride)
        s += u2f_ord(mins[i]);
    #pragma unroll
    for (int off = 32; off > 0; off >>= 1)
        s += __shfl_down(s, off, 64);
    __shared__ float wsum[4];
    int lane = threadIdx.x & 63;
    int wv   = threadIdx.x >> 6;
    if (lane == 0) wsum[wv] = s;
    __syncthreads();
    if (threadIdx.x == 0) {
        float t = wsum[0] + wsum[1] + wsum[2] + wsum[3];
        atomicAdd(out, t * (1.0f / (float)(B * N)));
    }
}

extern "C" void kernel_launch(void* const* d_in, const int* in_sizes, int n_in,
                              void* d_out, int out_size, void* d_ws, size_t ws_size,
                              hipStream_t stream) {
    const float* pred = (const float*)d_in[0];
    const float* gt   = (const float*)d_in[1];
    unsigned int* minP = (unsigned int*)d_ws;
    unsigned int* minG = minP + (size_t)B * N;
    float* out = (float*)d_out;

    int total = 2 * B * N;  // 131072
    init_kernel<<<(total + TPB - 1) / TPB, TPB, 0, stream>>>(minP, total, out);

    int blocks = 2 * B * NQ * NR;  // 1024
    chamfer_min_kernel<<<blocks, TPB, 0, stream>>>(pred, gt, minP, minG);

    chamfer_reduce_kernel<<<128, TPB, 0, stream>>>(minP, out, total);
}

// Round 4
// 138.544 us; speedup vs baseline: 1.7941x; 1.0483x over previous
//
#include <hip/hip_runtime.h>

// Chamfer distance, B=8, N=M=8192, D=3, fp32.
// dist(p,g) = p^2 + g^2 - 2 p.g  (same expansion as the JAX reference)
// Per query p: min_g dist = p^2 + min_g (g^2 - 2 p.g)   -> 3 FMA + min3/2 per pair.

constexpr int B   = 8;
constexpr int N   = 8192;
constexpr int TPB = 256;
constexpr int QPT = 8;            // query points per thread
constexpr int QPB = TPB * QPT;    // 2048 queries per block
constexpr int RCH = 256;          // reference points staged in LDS per block
constexpr int NQ  = N / QPB;      // 4
constexpr int NR  = N / RCH;      // 32
// grid = 2 * B * NQ * NR = 2048 blocks = 8 blocks/CU -> 32 waves/CU (100%)

// Order-preserving float->uint encoding (works for negatives too).
__device__ __forceinline__ unsigned int f2u_ord(float f) {
    unsigned int u = __float_as_uint(f);
    return (u & 0x80000000u) ? ~u : (u | 0x80000000u);
}
__device__ __forceinline__ float u2f_ord(unsigned int k) {
    unsigned int u = (k & 0x80000000u) ? (k & 0x7FFFFFFFu) : ~k;
    return __uint_as_float(u);
}

__global__ __launch_bounds__(TPB) void init_kernel(uint4* mins4, int n4, float* out) {
    int i = blockIdx.x * blockDim.x + threadIdx.x;
    const unsigned int INF = 0xFF800000u;  // f2u_ord(+inf)
    if (i < n4) mins4[i] = make_uint4(INF, INF, INF, INF);
    if (i == 0) out[0] = 0.0f;
}

__global__ __launch_bounds__(TPB) void chamfer_min_kernel(
    const float* __restrict__ pred, const float* __restrict__ gt,
    unsigned int* __restrict__ minP, unsigned int* __restrict__ minG) {
    int bid = blockIdx.x;
    int dir = bid / (B * NQ * NR);
    int rem = bid % (B * NQ * NR);
    int b   = rem / (NQ * NR);
    rem     = rem % (NQ * NR);
    int qc  = rem / NR;
    int rc  = rem % NR;

    const float* Q = (dir == 0) ? pred : gt;
    const float* R = (dir == 0) ? gt : pred;
    unsigned int* outMin = (dir == 0) ? minP : minG;

    __shared__ float4 lds[RCH];  // 4 KB: (gx, gy, gz, g^2)

    // Stage: exactly one point per thread (RCH == TPB).
    {
        int e = threadIdx.x;
        const float* rbase = R + ((size_t)b * N + (size_t)rc * RCH) * 3;
        float x = rbase[e * 3 + 0];
        float y = rbase[e * 3 + 1];
        float z = rbase[e * 3 + 2];
        float g2 = x * x + y * y + z * z;
        lds[e] = make_float4(x, y, z, g2);
    }
    __syncthreads();

    // Query registers: -2*q and |q|^2
    float m2x[QPT], m2y[QPT], m2z[QPT], q2[QPT], mn[QPT];
    const float* qbase = Q + ((size_t)b * N + (size_t)qc * QPB) * 3;
    #pragma unroll
    for (int q = 0; q < QPT; ++q) {
        int n = q * TPB + threadIdx.x;
        float x = qbase[n * 3 + 0];
        float y = qbase[n * 3 + 1];
        float z = qbase[n * 3 + 2];
        m2x[q] = -2.0f * x;
        m2y[q] = -2.0f * y;
        m2z[q] = -2.0f * z;
        q2[q]  = x * x + y * y + z * z;
        mn[q]  = __builtin_inff();
    }

    // Main loop: 4 reference points per iteration, min3 merges.
    #pragma unroll 1
    for (int j = 0; j < RCH; j += 4) {
        float4 g0 = lds[j];
        float4 g1 = lds[j + 1];
        float4 g2v = lds[j + 2];
        float4 g3 = lds[j + 3];
        #pragma unroll
        for (int q = 0; q < QPT; ++q) {
            float t0 = fmaf(m2x[q], g0.x, g0.w);
            t0 = fmaf(m2y[q], g0.y, t0);
            t0 = fmaf(m2z[q], g0.z, t0);
            float t1 = fmaf(m2x[q], g1.x, g1.w);
            t1 = fmaf(m2y[q], g1.y, t1);
            t1 = fmaf(m2z[q], g1.z, t1);
            float t2 = fmaf(m2x[q], g2v.x, g2v.w);
            t2 = fmaf(m2y[q], g2v.y, t2);
            t2 = fmaf(m2z[q], g2v.z, t2);
            float t3 = fmaf(m2x[q], g3.x, g3.w);
            t3 = fmaf(m2y[q], g3.y, t3);
            t3 = fmaf(m2z[q], g3.z, t3);
            mn[q] = fminf(mn[q], fminf(t0, t1));  // -> v_min3_f32
            mn[q] = fminf(mn[q], fminf(t2, t3));  // -> v_min3_f32
        }
    }

    #pragma unroll
    for (int q = 0; q < QPT; ++q) {
        int n = qc * QPB + q * TPB + threadIdx.x;
        atomicMin(&outMin[b * N + n], f2u_ord(q2[q] + mn[q]));
    }
}

__global__ __launch_bounds__(TPB) void chamfer_reduce_kernel(
    const unsigned int* __restrict__ mins, float* __restrict__ out, int total) {
    int i0 = blockIdx.x * blockDim.x + threadIdx.x;
    int stride = gridDim.x * blockDim.x;
    float s = 0.0f;
    for (int i = i0; i < total; i += stride)
        s += u2f_ord(mins[i]);
    #pragma unroll
    for (int off = 32; off > 0; off >>= 1)
        s += __shfl_down(s, off, 64);
    __shared__ float wsum[4];
    int lane = threadIdx.x & 63;
    int wv   = threadIdx.x >> 6;
    if (lane == 0) wsum[wv] = s;
    __syncthreads();
    if (threadIdx.x == 0) {
        float t = wsum[0] + wsum[1] + wsum[2] + wsum[3];
        atomicAdd(out, t * (1.0f / (float)(B * N)));
    }
}

extern "C" void kernel_launch(void* const* d_in, const int* in_sizes, int n_in,
                              void* d_out, int out_size, void* d_ws, size_t ws_size,
                              hipStream_t stream) {
    const float* pred = (const float*)d_in[0];
    const float* gt   = (const float*)d_in[1];
    unsigned int* minP = (unsigned int*)d_ws;
    unsigned int* minG = minP + (size_t)B * N;
    float* out = (float*)d_out;

    int total = 2 * B * N;  // 131072
    int n4 = total / 4;     // 32768 uint4
    init_kernel<<<(n4 + TPB - 1) / TPB, TPB, 0, stream>>>((uint4*)d_ws, n4, out);

    int blocks = 2 * B * NQ * NR;  // 2048
    chamfer_min_kernel<<<blocks, TPB, 0, stream>>>(pred, gt, minP, minG);

    chamfer_reduce_kernel<<<128, TPB, 0, stream>>>(minP, out, total);
}